// Round 24
// baseline (120.112 us; speedup 1.0000x reference)
//
#include <hip/hip_runtime.h>
#include <hip/hip_bf16.h>

// ---------------- types ----------------
typedef __bf16 bf16;
typedef __attribute__((ext_vector_type(2))) __bf16 bf16x2;
typedef __attribute__((ext_vector_type(4))) __bf16 bf16x4;
typedef __attribute__((ext_vector_type(8))) __bf16 bf16x8;
typedef __attribute__((ext_vector_type(4))) float f32x4;
typedef __attribute__((ext_vector_type(16))) float f32x16;
typedef unsigned int u32;
typedef __attribute__((ext_vector_type(4))) u32 u32x4;
typedef const __attribute__((address_space(1))) u32* gptr_t;
typedef __attribute__((address_space(3))) u32* lptr_t;

#define N_EMB 1024
#define N_HEAD 16
#define HEAD_DIM 64
#define T_SEQ 2048
#define BATCH 2
#define M_TOT (BATCH * T_SEQ)   // 4096
#define N_QKV (3 * N_EMB)       // 3072
#define KDIM 1024
// scale * log2(e), folded into Q at the QKV epilogue
#define CS_LOG2E 0.1803368801111129f

// round-to-nearest-even f32 -> bf16
__device__ inline unsigned short f2bu(float f) {
    unsigned u = __builtin_bit_cast(unsigned, f);
    return (unsigned short)((u + 0x7fffu + ((u >> 16) & 1u)) >> 16);
}
__device__ inline bf16 f2b(float f) {
    unsigned short s = f2bu(f);
    return __builtin_bit_cast(bf16, s);
}
__device__ inline u32 pkbf(float lo, float hi) {
    bf16x2 t; t[0] = (bf16)lo; t[1] = (bf16)hi;
    return __builtin_bit_cast(u32, t);
}
__device__ __forceinline__ float xhalf_sum(float x) {
    return x + __shfl_xor(x, 32, 64);
}
// full LDS drain + scheduler fence (rule #18): placed after ALL fragment
// ds_reads from a buffer, strictly before async staging re-targets it.
__device__ __forceinline__ void lds_fence() {
    asm volatile("s_waitcnt lgkmcnt(0)" ::: "memory");
    __builtin_amdgcn_sched_barrier(0);
}

// ---------------- fused prep: cast x + transpose both weights ----------------
__global__ __launch_bounds__(256) void k_prep(const float* __restrict__ x,
                                              const float* __restrict__ W_attn,
                                              const float* __restrict__ W_proj,
                                              bf16* __restrict__ xb,
                                              bf16* __restrict__ wat,
                                              bf16* __restrict__ wpt) {
    const int id = blockIdx.x;
    if (id < 4096) {
        int i = id * 256 + threadIdx.x;
        float4 v = reinterpret_cast<const float4*>(x)[i];
        ushort4 u;
        u.x = f2bu(v.x); u.y = f2bu(v.y); u.z = f2bu(v.z); u.w = f2bu(v.w);
        reinterpret_cast<ushort4*>(xb)[i] = u;
        return;
    }
    __shared__ float tile[32][33];
    const float* W; bf16* Wt; int N, bid;
    if (id < 7168) { W = W_attn; Wt = wat; N = N_QKV; bid = id - 4096; }
    else           { W = W_proj; Wt = wpt; N = N_EMB; bid = id - 7168; }
    const int k0 = (bid & 31) * 32;
    const int n0 = (bid >> 5) * 32;
    const int tx = threadIdx.x & 31;
    const int ty = threadIdx.x >> 5;
    for (int j = 0; j < 32; j += 8)
        tile[ty + j][tx] = W[(k0 + ty + j) * N + n0 + tx];
    __syncthreads();
    for (int j = 0; j < 32; j += 8)
        Wt[(n0 + ty + j) * (long)KDIM + k0 + tx] = f2b(tile[tx][ty + j]);
}

// ---------------- V transpose+k-permute: [B,H,T,64] -> [B,H,64,T'] ----------------
__global__ __launch_bounds__(256) void k_vtrans(const bf16* __restrict__ v,
                                                bf16* __restrict__ vt) {
    __shared__ bf16 tile[64 * 76];
    const int bh = blockIdx.y;
    const int t0 = blockIdx.x * 64;
    const bf16* src = v + (size_t)bh * T_SEQ * HEAD_DIM;
    bf16* dst = vt + (size_t)bh * HEAD_DIM * T_SEQ;
    const int tid = threadIdx.x;
    #pragma unroll
    for (int it = 0; it < 2; ++it) {
        const int row = (tid >> 3) + it * 32;
        const int col = (tid & 7) * 8;
        bf16x8 val = *reinterpret_cast<const bf16x8*>(src + (size_t)(t0 + row) * HEAD_DIM + col);
        bf16x4 lo;  lo[0] = val[0]; lo[1] = val[1]; lo[2] = val[2]; lo[3] = val[3];
        bf16x4 hiv; hiv[0] = val[4]; hiv[1] = val[5]; hiv[2] = val[6]; hiv[3] = val[7];
        *reinterpret_cast<bf16x4*>(&tile[row * 76 + col]) = lo;
        *reinterpret_cast<bf16x4*>(&tile[row * 76 + col + 4]) = hiv;
    }
    __syncthreads();
    #pragma unroll
    for (int it = 0; it < 2; ++it) {
        const int d  = (tid >> 3) + it * 32;
        const int tt = (tid & 7) * 8;
        bf16x8 val;
        #pragma unroll
        for (int q = 0; q < 8; ++q) {
            const int pq = tt + q;
            const int sw = ((pq >> 2) ^ (pq >> 3)) & 1;
            const int ps = sw ? (pq ^ 12) : pq;
            val[q] = tile[ps * 76 + d];
        }
        *reinterpret_cast<bf16x8*>(dst + (size_t)d * T_SEQ + t0 + tt) = val;
    }
}

// =====================================================================
// 128x128 GEMM main loop (m97 structure) — used by QKV and proj
// =====================================================================
#define GEMM_MAINLOOP(A_, Bt_, m0_, n0_)                                          \
    __shared__ __align__(16) bf16 As[128 * 32];                                   \
    __shared__ __align__(16) bf16 Bs[128 * 32];                                   \
    const int lane = threadIdx.x & 63;                                            \
    const int w    = threadIdx.x >> 6;                                            \
    const int wr   = w >> 1;                                                      \
    const int wc   = w & 1;                                                       \
    const int r    = lane & 15;                                                   \
    const int ko   = (lane >> 4) * 8;                                             \
    const int srow = w * 32 + (lane >> 2);                                        \
    const int sk   = (lane & 3) * 8;                                              \
    const bf16* a_g0 = A_ + (size_t)(m0_ + srow) * KDIM + sk;                     \
    const bf16* a_g1 = a_g0 + 16 * KDIM;                                          \
    const bf16* b_g0 = Bt_ + (size_t)(n0_ + srow) * KDIM + sk;                    \
    const bf16* b_g1 = b_g0 + 16 * KDIM;                                          \
    bf16* a_l0 = As + (w * 2) * 512;                                              \
    bf16* a_l1 = As + (w * 2 + 1) * 512;                                          \
    bf16* b_l0 = Bs + (w * 2) * 512;                                              \
    bf16* b_l1 = Bs + (w * 2 + 1) * 512;                                          \
    f32x4 acc[4][4];                                                              \
    for (int i = 0; i < 4; ++i)                                                   \
        for (int j = 0; j < 4; ++j) acc[i][j] = (f32x4){0.f, 0.f, 0.f, 0.f};      \
    for (int k0 = 0; k0 < KDIM; k0 += 32) {                                       \
        __builtin_amdgcn_global_load_lds((gptr_t)(const void*)(a_g0 + k0),        \
                                         (lptr_t)(void*)a_l0, 16, 0, 0);          \
        __builtin_amdgcn_global_load_lds((gptr_t)(const void*)(a_g1 + k0),        \
                                         (lptr_t)(void*)a_l1, 16, 0, 0);          \
        __builtin_amdgcn_global_load_lds((gptr_t)(const void*)(b_g0 + k0),        \
                                         (lptr_t)(void*)b_l0, 16, 0, 0);          \
        __builtin_amdgcn_global_load_lds((gptr_t)(const void*)(b_g1 + k0),        \
                                         (lptr_t)(void*)b_l1, 16, 0, 0);          \
        __syncthreads();                                                          \
        bf16x8 af[4], bfr[4];                                                     \
        for (int m = 0; m < 4; ++m)                                               \
            af[m] = *reinterpret_cast<const bf16x8*>(As + (wr * 64 + m * 16 + r) * 32 + ko); \
        for (int n = 0; n < 4; ++n)                                               \
            bfr[n] = *reinterpret_cast<const bf16x8*>(Bs + (wc * 64 + n * 16 + r) * 32 + ko); \
        for (int m = 0; m < 4; ++m)                                               \
            for (int n = 0; n < 4; ++n)                                           \
                acc[m][n] = __builtin_amdgcn_mfma_f32_16x16x32_bf16(af[m], bfr[n], acc[m][n], 0, 0, 0); \
        __syncthreads();                                                          \
    }

// ---------------- QKV GEMM -> q/k/v [B,H,T,64] bf16 (q pre-scaled by CS_LOG2E) ----------------
__global__ __launch_bounds__(256) void k_gemm_qkv(const bf16* __restrict__ A,
                                                  const bf16* __restrict__ Bt,
                                                  const float* __restrict__ bias,
                                                  bf16* __restrict__ qb,
                                                  bf16* __restrict__ kb,
                                                  bf16* __restrict__ vb) {
    const int m0 = blockIdx.x * 128;
    const int n0 = blockIdx.y * 128;
    GEMM_MAINLOOP(A, Bt, m0, n0)
    const int col   = lane & 15;
    const int rbase = (lane >> 4) * 4;
    for (int nn = 0; nn < 4; ++nn) {
        int n = n0 + wc * 64 + nn * 16 + col;
        float bv = bias[n];
        int which = n >> 10;
        int c  = n & 1023;
        int h  = c >> 6;
        int dh = c & 63;
        bf16* dst = (which == 0) ? qb : ((which == 1) ? kb : vb);
        const float sc = (which == 0) ? CS_LOG2E : 1.0f;
        for (int mm = 0; mm < 4; ++mm) {
            for (int i = 0; i < 4; ++i) {
                int m = m0 + wr * 64 + mm * 16 + rbase + i;
                int b_ = m >> 11;
                int t  = m & 2047;
                dst[(((b_ * N_HEAD + h) * T_SEQ) + t) * HEAD_DIM + dh] =
                    f2b((acc[mm][nn][i] + bv) * sc);
            }
        }
    }
}

// ---------------- proj GEMM (128x128 tiles) ----------------
__global__ __launch_bounds__(256) void k_gemm_proj(const bf16* __restrict__ A,
                                                   const bf16* __restrict__ Bt,
                                                   const float* __restrict__ bias,
                                                   float* __restrict__ out) {
    const int m0 = blockIdx.x * 128;
    const int n0 = blockIdx.y * 128;
    GEMM_MAINLOOP(A, Bt, m0, n0)
    const int col   = lane & 15;
    const int rbase = (lane >> 4) * 4;
    for (int nn = 0; nn < 4; ++nn) {
        int n = n0 + wc * 64 + nn * 16 + col;
        float bv = bias[n];
        for (int mm = 0; mm < 4; ++mm) {
            for (int i = 0; i < 4; ++i) {
                int m = m0 + wr * 64 + mm * 16 + rbase + i;
                out[(size_t)m * N_EMB + n] = acc[mm][nn][i] + bv;
            }
        }
    }
}

// =====================================================================
// flash attention helpers. Fixed-max softmax (Q pre-scaled, log2 units).
// R24: DEPTH-2 double-buffered pipeline with COUNTED vmcnt (T3+T4).
// Invariant at steady-state loop top: 16 loads outstanding (t's 8 oldest
// + t+1's 8). vmcnt(8) drains exactly t's; t+1's stay in flight across
// the whole compute of t. After fragment reads + fence, t+2's 8 are
// issued into the just-consumed buffer. Never drains to 0 mid-loop.
// =====================================================================
__device__ __forceinline__ void pv_group(const float* p,
                                         const bf16x8 (&va)[2][2], f32x16 (&o)[2]) {
    u32x4 f0, f1;
    f0[0] = pkbf(p[0], p[1]);   f0[1] = pkbf(p[2], p[3]);
    f0[2] = pkbf(p[4], p[5]);   f0[3] = pkbf(p[6], p[7]);
    f1[0] = pkbf(p[8], p[9]);   f1[1] = pkbf(p[10], p[11]);
    f1[2] = pkbf(p[12], p[13]); f1[3] = pkbf(p[14], p[15]);
    bf16x8 pb0 = __builtin_bit_cast(bf16x8, f0);
    bf16x8 pb1 = __builtin_bit_cast(bf16x8, f1);
    __builtin_amdgcn_s_setprio(1);
    #pragma unroll
    for (int dt = 0; dt < 2; ++dt) {
        o[dt] = __builtin_amdgcn_mfma_f32_32x32x16_bf16(va[dt][0], pb0, o[dt], 0, 0, 0);
        o[dt] = __builtin_amdgcn_mfma_f32_32x32x16_bf16(va[dt][1], pb1, o[dt], 0, 0, 0);
    }
    __builtin_amdgcn_s_setprio(0);
}

__device__ __forceinline__ void stage_k32(const char* Kg, char* Ks, int kbase, int lane) {
    #pragma unroll
    for (int rr = 0; rr < 4; ++rr) {
        const int fb  = rr * 1024 + lane * 16;
        const int row = fb >> 7;
        const int swz = (row & 7) << 4;
        __builtin_amdgcn_global_load_lds(
            (gptr_t)(const void*)(Kg + (size_t)kbase * 128 + (fb ^ swz)),
            (lptr_t)(void*)(Ks + rr * 1024), 16, 0, 0);
    }
}
__device__ __forceinline__ void stage_v32(const char* Vg, char* Vs, int kbase, int lane) {
    #pragma unroll
    for (int rr = 0; rr < 4; ++rr) {
        const int fb  = rr * 1024 + lane * 16;
        const int d   = fb >> 6;
        const int off = fb & 63;
        const int swz = (d & 3) << 4;
        __builtin_amdgcn_global_load_lds(
            (gptr_t)(const void*)(Vg + (size_t)d * (T_SEQ * 2) + (size_t)kbase * 2 + (off ^ swz)),
            (lptr_t)(void*)(Vs + rr * 1024), 16, 0, 0);
    }
}

__device__ __forceinline__ void load_kf(const char* Ks, int qr, int hi, bf16x8 (&kf)[4]) {
    const int swzk = (qr & 7) << 4;
    #pragma unroll
    for (int f = 0; f < 4; ++f)
        kf[f] = *reinterpret_cast<const bf16x8*>(
            Ks + ((qr * 128 + f * 32 + hi * 16) ^ swzk));
}
__device__ __forceinline__ void load_va(const char* Vs, int qr, int hi, bf16x8 (&va)[2][2]) {
    #pragma unroll
    for (int dt = 0; dt < 2; ++dt)
        #pragma unroll
        for (int ks = 0; ks < 2; ++ks) {
            const int d = dt * 32 + qr;
            va[dt][ks] = *reinterpret_cast<const bf16x8*>(
                Vs + ((d * 64 + ks * 32 + hi * 16) ^ ((d & 3) << 4)));
        }
}

__device__ __forceinline__ f32x16 qkt_tile(const bf16x8 (&kf)[4], const bf16x8 (&qf)[4]) {
    f32x16 st;
    #pragma unroll
    for (int r = 0; r < 16; ++r) st[r] = 0.f;
    __builtin_amdgcn_s_setprio(1);
    #pragma unroll
    for (int f = 0; f < 4; ++f)
        st = __builtin_amdgcn_mfma_f32_32x32x16_bf16(kf[f], qf[f], st, 0, 0, 0);
    __builtin_amdgcn_s_setprio(0);
    return st;
}

__device__ __forceinline__ void softmax_pv(f32x16 st, const bf16x8 (&va)[2][2],
                                           int qr, int hi, bool diag,
                                           float& l_r, f32x16 (&o)[2]) {
    if (diag) {
        const int kp4 = 4 * hi;
        #pragma unroll
        for (int r = 0; r < 16; ++r) {
            const int kpos = (r & 3) + 8 * (r >> 2) + kp4;
            if (kpos > qr) st[r] = -3.0e38f;
        }
    }
    float p[16];
    #pragma unroll
    for (int r = 0; r < 16; ++r) p[r] = exp2f(st[r]);   // masked -3e38 underflows to 0
    float s = 0.f;
    #pragma unroll
    for (int r = 0; r < 8; ++r) s += p[r] + p[r + 8];
    l_r += s;
    pv_group(p, va, o);
}

// =====================================================================
// flash attention: block = (bh, qblk), 4 waves, 4-way split-K. Each wave
// has a PRIVATE 16KB double-buffered LDS slice (2 x (K 4KB + V 4KB)).
// Depth-2 counted-vmcnt pipeline: t+1's loads fly across all of t's
// compute. 64KB/block -> 2 blocks/CU. 2048 blocks, heavy-first,
// XCD-pinned bh. Combine via bf16 slab in own slice.
// =====================================================================
__global__ __launch_bounds__(256) void k_attn(const bf16* __restrict__ qb,
                                              const bf16* __restrict__ kb,
                                              const bf16* __restrict__ vtb,
                                              bf16* __restrict__ yb) {
    const int lane = threadIdx.x & 63;
    const int wv   = threadIdx.x >> 6;   // 0..3
    const int bh   = blockIdx.x;         // 0..31  (XCD = bh % 8)
    const int qblk = 63 - blockIdx.y;    // heavy-first
    const int q0   = qblk * 32;
    const int b    = bh >> 4;
    const int h    = bh & 15;

    const char* Qg = (const char*)(qb  + (size_t)bh * T_SEQ * HEAD_DIM);
    const char* Kg = (const char*)(kb  + (size_t)bh * T_SEQ * HEAD_DIM);
    const char* Vg = (const char*)(vtb + (size_t)bh * HEAD_DIM * T_SEQ);

    const int qr = lane & 31;
    const int hi = lane >> 5;

    __shared__ __align__(16) char sbuf[4][16384];  // per-wave 2x8KB slices; 64KB
    char* Ks0 = sbuf[wv];
    char* Vs0 = sbuf[wv] + 4096;
    char* Ks1 = sbuf[wv] + 8192;
    char* Vs1 = sbuf[wv] + 12288;

    // ---- Q fragments: stage via buf0 (coalesced), then read ----
    stage_k32(Qg, Ks0, qblk * 32, lane);
    asm volatile("s_waitcnt vmcnt(0)" ::: "memory");
    bf16x8 qf[4];
    load_kf(Ks0, qr, hi, qf);
    lds_fence();   // RACE FIX (R17): qf reads drained before staging overwrites

    f32x16 o[2];
    #pragma unroll
    for (int r = 0; r < 16; ++r) { o[0][r] = 0.f; o[1][r] = 0.f; }
    float l_r = 0.f;

    // 4-way split-K: wave wv owns a contiguous chunk; last chunk has diag.
    const int n    = qblk + 1;
    const int base = n >> 2;
    const int rem  = n & 3;
    const int lo   = wv * base + (wv < rem ? wv : rem);
    const int cnt  = base + (wv < rem ? 1 : 0);
    const int end  = lo + cnt;

    if (cnt > 0) {
        // prologue: fill both pipeline stages (8 loads each)
        stage_k32(Kg, Ks0, lo * 32, lane);
        stage_v32(Vg, Vs0, lo * 32, lane);
        if (lo + 1 < end) {
            stage_k32(Kg, Ks1, (lo + 1) * 32, lane);
            stage_v32(Vg, Vs1, (lo + 1) * 32, lane);
        }
        for (int t = lo; t < end; ++t) {
            char* Kc = ((t - lo) & 1) ? Ks1 : Ks0;
            char* Vc = ((t - lo) & 1) ? Vs1 : Vs0;
            // counted drain: t's 8 are the oldest of 16 outstanding;
            // t+1's 8 stay in flight. Last tile: drain all.
            if (t + 1 < end)
                asm volatile("s_waitcnt vmcnt(8)" ::: "memory");
            else
                asm volatile("s_waitcnt vmcnt(0)" ::: "memory");
            bf16x8 kf[4];
            load_kf(Kc, qr, hi, kf);
            f32x16 st = qkt_tile(kf, qf);
            bf16x8 va[2][2];
            load_va(Vc, qr, hi, va);
            lds_fence();                        // this buffer's reads drained
            if (t + 2 < end) {                  // refill the freed buffer for t+2
                stage_k32(Kg, Kc, (t + 2) * 32, lane);
                stage_v32(Vg, Vc, (t + 2) * 32, lane);
            }
            softmax_pv(st, va, qr, hi, t == qblk, l_r, o);
        }
    }

    // ---- combine across 4 waves via own slice: bf16 o slab + f32 l ----
    if (wv > 0) {
        bf16* so = (bf16*)sbuf[wv];
        #pragma unroll
        for (int i = 0; i < 16; ++i) {
            so[i * 64 + lane]        = f2b(o[0][i]);
            so[(16 + i) * 64 + lane] = f2b(o[1][i]);
        }
        *reinterpret_cast<float*>(sbuf[wv] + 4096 + lane * 4) = l_r;
    }
    __syncthreads();
    if (wv > 0) return;
    #pragma unroll
    for (int s = 1; s < 4; ++s) {
        const bf16* so = (const bf16*)sbuf[s];
        l_r += *reinterpret_cast<const float*>(sbuf[s] + 4096 + lane * 4);
        #pragma unroll
        for (int i = 0; i < 16; ++i) {
            o[0][i] += (float)so[i * 64 + lane];
            o[1][i] += (float)so[(16 + i) * 64 + lane];
        }
    }
    l_r = xhalf_sum(l_r);

    // ---- epilogue: O^T[d][q] / l -> y[b][t][h*64+d] ----
    const float inv = 1.f / fmaxf(l_r, 1e-30f);
    const int tq = q0 + qr;
    bf16* yrow = yb + ((size_t)(b * T_SEQ + tq)) * N_EMB + h * HEAD_DIM;
    #pragma unroll
    for (int dt = 0; dt < 2; ++dt) {
        #pragma unroll
        for (int rr = 0; rr < 4; ++rr) {
            const int d0 = dt * 32 + 8 * rr + 4 * hi;
            ushort4 u;
            u.x = f2bu(o[dt][4 * rr + 0] * inv);
            u.y = f2bu(o[dt][4 * rr + 1] * inv);
            u.z = f2bu(o[dt][4 * rr + 2] * inv);
            u.w = f2bu(o[dt][4 * rr + 3] * inv);
            *reinterpret_cast<ushort4*>(yrow + d0) = u;
        }
    }
}

extern "C" void kernel_launch(void* const* d_in, const int* in_sizes, int n_in,
                              void* d_out, int out_size, void* d_ws, size_t ws_size,
                              hipStream_t stream) {
    const float* x      = (const float*)d_in[0];
    const float* W_attn = (const float*)d_in[1];
    const float* b_attn = (const float*)d_in[2];
    const float* W_proj = (const float*)d_in[3];
    const float* b_proj = (const float*)d_in[4];
    float* out = (float*)d_out;

    const size_t sz_x   = (size_t)M_TOT * N_EMB;
    const size_t sz_wat = (size_t)N_QKV * N_EMB;
    const size_t sz_wpt = (size_t)N_EMB * N_EMB;
    const size_t sz_hd  = (size_t)BATCH * N_HEAD * T_SEQ * HEAD_DIM;
    const size_t need = (sz_x + sz_wat + sz_wpt + 3 * sz_hd + sz_x) * sizeof(bf16);
    if (ws_size < need) return;

    bf16* xb  = (bf16*)d_ws;       // dead after QKV GEMM -> reused for V^T
    bf16* wat = xb + sz_x;
    bf16* wpt = wat + sz_wat;
    bf16* qb  = wpt + sz_wpt;
    bf16* kbf = qb + sz_hd;
    bf16* vbf = kbf + sz_hd;
    bf16* yb  = vbf + sz_hd;
    bf16* vtb = xb;                // V^T [B,H,64,T] (k-permuted)

    k_prep<<<dim3(8192), 256, 0, stream>>>(x, W_attn, W_proj, xb, wat, wpt);
    k_gemm_qkv<<<dim3(M_TOT / 128, N_QKV / 128), 256, 0, stream>>>(xb, wat, b_attn, qb, kbf, vbf);
    k_vtrans<<<dim3(T_SEQ / 64, BATCH * N_HEAD), 256, 0, stream>>>(vbf, vtb);
    k_attn<<<dim3(BATCH * N_HEAD, 64), 256, 0, stream>>>(qb, kbf, vtb, yb);
    k_gemm_proj<<<dim3(M_TOT / 128, N_EMB / 128), 256, 0, stream>>>(yb, wpt, b_proj, out);
}

// Round 25
// 111.931 us; speedup vs baseline: 1.0731x; 1.0731x over previous
//
#include <hip/hip_runtime.h>
#include <hip/hip_bf16.h>

// ---------------- types ----------------
typedef __bf16 bf16;
typedef __attribute__((ext_vector_type(2))) __bf16 bf16x2;
typedef __attribute__((ext_vector_type(4))) __bf16 bf16x4;
typedef __attribute__((ext_vector_type(8))) __bf16 bf16x8;
typedef __attribute__((ext_vector_type(4))) float f32x4;
typedef __attribute__((ext_vector_type(16))) float f32x16;
typedef unsigned int u32;
typedef __attribute__((ext_vector_type(4))) u32 u32x4;
typedef const __attribute__((address_space(1))) u32* gptr_t;
typedef __attribute__((address_space(3))) u32* lptr_t;

#define N_EMB 1024
#define N_HEAD 16
#define HEAD_DIM 64
#define T_SEQ 2048
#define BATCH 2
#define M_TOT (BATCH * T_SEQ)   // 4096
#define N_QKV (3 * N_EMB)       // 3072
#define KDIM 1024
// scale * log2(e), folded into Q at the QKV epilogue
#define CS_LOG2E 0.1803368801111129f

// round-to-nearest-even f32 -> bf16
__device__ inline unsigned short f2bu(float f) {
    unsigned u = __builtin_bit_cast(unsigned, f);
    return (unsigned short)((u + 0x7fffu + ((u >> 16) & 1u)) >> 16);
}
__device__ inline bf16 f2b(float f) {
    unsigned short s = f2bu(f);
    return __builtin_bit_cast(bf16, s);
}
__device__ inline u32 pkbf(float lo, float hi) {
    bf16x2 t; t[0] = (bf16)lo; t[1] = (bf16)hi;
    return __builtin_bit_cast(u32, t);
}
__device__ __forceinline__ float xhalf_sum(float x) {
    return x + __shfl_xor(x, 32, 64);
}
// full LDS drain + scheduler fence (rule #18): placed after ALL fragment
// ds_reads, strictly before async staging overwrites the same LDS.
__device__ __forceinline__ void lds_fence() {
    asm volatile("s_waitcnt lgkmcnt(0)" ::: "memory");
    __builtin_amdgcn_sched_barrier(0);
}

// ---------------- fused prep: cast x + transpose both weights ----------------
__global__ __launch_bounds__(256) void k_prep(const float* __restrict__ x,
                                              const float* __restrict__ W_attn,
                                              const float* __restrict__ W_proj,
                                              bf16* __restrict__ xb,
                                              bf16* __restrict__ wat,
                                              bf16* __restrict__ wpt) {
    const int id = blockIdx.x;
    if (id < 4096) {
        int i = id * 256 + threadIdx.x;
        float4 v = reinterpret_cast<const float4*>(x)[i];
        ushort4 u;
        u.x = f2bu(v.x); u.y = f2bu(v.y); u.z = f2bu(v.z); u.w = f2bu(v.w);
        reinterpret_cast<ushort4*>(xb)[i] = u;
        return;
    }
    __shared__ float tile[32][33];
    const float* W; bf16* Wt; int N, bid;
    if (id < 7168) { W = W_attn; Wt = wat; N = N_QKV; bid = id - 4096; }
    else           { W = W_proj; Wt = wpt; N = N_EMB; bid = id - 7168; }
    const int k0 = (bid & 31) * 32;
    const int n0 = (bid >> 5) * 32;
    const int tx = threadIdx.x & 31;
    const int ty = threadIdx.x >> 5;
    for (int j = 0; j < 32; j += 8)
        tile[ty + j][tx] = W[(k0 + ty + j) * N + n0 + tx];
    __syncthreads();
    for (int j = 0; j < 32; j += 8)
        Wt[(n0 + ty + j) * (long)KDIM + k0 + tx] = f2b(tile[tx][ty + j]);
}

// ---------------- V transpose+k-permute: [B,H,T,64] -> [B,H,64,T'] ----------------
__global__ __launch_bounds__(256) void k_vtrans(const bf16* __restrict__ v,
                                                bf16* __restrict__ vt) {
    __shared__ bf16 tile[64 * 76];
    const int bh = blockIdx.y;
    const int t0 = blockIdx.x * 64;
    const bf16* src = v + (size_t)bh * T_SEQ * HEAD_DIM;
    bf16* dst = vt + (size_t)bh * HEAD_DIM * T_SEQ;
    const int tid = threadIdx.x;
    #pragma unroll
    for (int it = 0; it < 2; ++it) {
        const int row = (tid >> 3) + it * 32;
        const int col = (tid & 7) * 8;
        bf16x8 val = *reinterpret_cast<const bf16x8*>(src + (size_t)(t0 + row) * HEAD_DIM + col);
        bf16x4 lo;  lo[0] = val[0]; lo[1] = val[1]; lo[2] = val[2]; lo[3] = val[3];
        bf16x4 hiv; hiv[0] = val[4]; hiv[1] = val[5]; hiv[2] = val[6]; hiv[3] = val[7];
        *reinterpret_cast<bf16x4*>(&tile[row * 76 + col]) = lo;
        *reinterpret_cast<bf16x4*>(&tile[row * 76 + col + 4]) = hiv;
    }
    __syncthreads();
    #pragma unroll
    for (int it = 0; it < 2; ++it) {
        const int d  = (tid >> 3) + it * 32;
        const int tt = (tid & 7) * 8;
        bf16x8 val;
        #pragma unroll
        for (int q = 0; q < 8; ++q) {
            const int pq = tt + q;
            const int sw = ((pq >> 2) ^ (pq >> 3)) & 1;
            const int ps = sw ? (pq ^ 12) : pq;
            val[q] = tile[ps * 76 + d];
        }
        *reinterpret_cast<bf16x8*>(dst + (size_t)d * T_SEQ + t0 + tt) = val;
    }
}

// =====================================================================
// 128x128 GEMM main loop (m97 structure) — used by QKV
// =====================================================================
#define GEMM_MAINLOOP(A_, Bt_, m0_, n0_)                                          \
    __shared__ __align__(16) bf16 As[128 * 32];                                   \
    __shared__ __align__(16) bf16 Bs[128 * 32];                                   \
    const int lane = threadIdx.x & 63;                                            \
    const int w    = threadIdx.x >> 6;                                            \
    const int wr   = w >> 1;                                                      \
    const int wc   = w & 1;                                                       \
    const int r    = lane & 15;                                                   \
    const int ko   = (lane >> 4) * 8;                                             \
    const int srow = w * 32 + (lane >> 2);                                        \
    const int sk   = (lane & 3) * 8;                                              \
    const bf16* a_g0 = A_ + (size_t)(m0_ + srow) * KDIM + sk;                     \
    const bf16* a_g1 = a_g0 + 16 * KDIM;                                          \
    const bf16* b_g0 = Bt_ + (size_t)(n0_ + srow) * KDIM + sk;                    \
    const bf16* b_g1 = b_g0 + 16 * KDIM;                                          \
    bf16* a_l0 = As + (w * 2) * 512;                                              \
    bf16* a_l1 = As + (w * 2 + 1) * 512;                                          \
    bf16* b_l0 = Bs + (w * 2) * 512;                                              \
    bf16* b_l1 = Bs + (w * 2 + 1) * 512;                                          \
    f32x4 acc[4][4];                                                              \
    for (int i = 0; i < 4; ++i)                                                   \
        for (int j = 0; j < 4; ++j) acc[i][j] = (f32x4){0.f, 0.f, 0.f, 0.f};      \
    for (int k0 = 0; k0 < KDIM; k0 += 32) {                                       \
        __builtin_amdgcn_global_load_lds((gptr_t)(const void*)(a_g0 + k0),        \
                                         (lptr_t)(void*)a_l0, 16, 0, 0);          \
        __builtin_amdgcn_global_load_lds((gptr_t)(const void*)(a_g1 + k0),        \
                                         (lptr_t)(void*)a_l1, 16, 0, 0);          \
        __builtin_amdgcn_global_load_lds((gptr_t)(const void*)(b_g0 + k0),        \
                                         (lptr_t)(void*)b_l0, 16, 0, 0);          \
        __builtin_amdgcn_global_load_lds((gptr_t)(const void*)(b_g1 + k0),        \
                                         (lptr_t)(void*)b_l1, 16, 0, 0);          \
        __syncthreads();                                                          \
        bf16x8 af[4], bfr[4];                                                     \
        for (int m = 0; m < 4; ++m)                                               \
            af[m] = *reinterpret_cast<const bf16x8*>(As + (wr * 64 + m * 16 + r) * 32 + ko); \
        for (int n = 0; n < 4; ++n)                                               \
            bfr[n] = *reinterpret_cast<const bf16x8*>(Bs + (wc * 64 + n * 16 + r) * 32 + ko); \
        for (int m = 0; m < 4; ++m)                                               \
            for (int n = 0; n < 4; ++n)                                           \
                acc[m][n] = __builtin_amdgcn_mfma_f32_16x16x32_bf16(af[m], bfr[n], acc[m][n], 0, 0, 0); \
        __syncthreads();                                                          \
    }

// =====================================================================
// 64x128 GEMM main loop — used by proj (R21-proven config)
// =====================================================================
#define GEMM_MAINLOOP_64(A_, Bt_, m0_, n0_)                                       \
    __shared__ __align__(16) bf16 As[64 * 32];                                    \
    __shared__ __align__(16) bf16 Bs[128 * 32];                                   \
    const int lane = threadIdx.x & 63;                                            \
    const int w    = threadIdx.x >> 6;                                            \
    const int wr   = w >> 1;                                                      \
    const int wc   = w & 1;                                                       \
    const int r    = lane & 15;                                                   \
    const int ko   = (lane >> 4) * 8;                                             \
    const int srow = w * 16 + (lane >> 2);                                        \
    const int sk   = (lane & 3) * 8;                                              \
    const bf16* a_g0 = A_ + (size_t)(m0_ + srow) * KDIM + sk;                     \
    const bf16* b_g0 = Bt_ + (size_t)(n0_ + srow) * KDIM + sk;                    \
    const bf16* b_g1 = b_g0 + 64 * KDIM;                                          \
    bf16* a_l0 = As + w * 512;                                                    \
    bf16* b_l0 = Bs + w * 512;                                                    \
    bf16* b_l1 = Bs + 64 * 32 + w * 512;                                          \
    f32x4 acc[2][4];                                                              \
    for (int i = 0; i < 2; ++i)                                                   \
        for (int j = 0; j < 4; ++j) acc[i][j] = (f32x4){0.f, 0.f, 0.f, 0.f};      \
    for (int k0 = 0; k0 < KDIM; k0 += 32) {                                       \
        __builtin_amdgcn_global_load_lds((gptr_t)(const void*)(a_g0 + k0),        \
                                         (lptr_t)(void*)a_l0, 16, 0, 0);          \
        __builtin_amdgcn_global_load_lds((gptr_t)(const void*)(b_g0 + k0),        \
                                         (lptr_t)(void*)b_l0, 16, 0, 0);          \
        __builtin_amdgcn_global_load_lds((gptr_t)(const void*)(b_g1 + k0),        \
                                         (lptr_t)(void*)b_l1, 16, 0, 0);          \
        __syncthreads();                                                          \
        bf16x8 af[2], bfr[4];                                                     \
        for (int m = 0; m < 2; ++m)                                               \
            af[m] = *reinterpret_cast<const bf16x8*>(As + (wr * 32 + m * 16 + r) * 32 + ko); \
        for (int n = 0; n < 4; ++n)                                               \
            bfr[n] = *reinterpret_cast<const bf16x8*>(Bs + (wc * 64 + n * 16 + r) * 32 + ko); \
        for (int m = 0; m < 2; ++m)                                               \
            for (int n = 0; n < 4; ++n)                                           \
                acc[m][n] = __builtin_amdgcn_mfma_f32_16x16x32_bf16(af[m], bfr[n], acc[m][n], 0, 0, 0); \
        __syncthreads();                                                          \
    }

// ---------------- QKV GEMM -> q/k/v [B,H,T,64] bf16 (q pre-scaled by CS_LOG2E) ----------------
__global__ __launch_bounds__(256) void k_gemm_qkv(const bf16* __restrict__ A,
                                                  const bf16* __restrict__ Bt,
                                                  const float* __restrict__ bias,
                                                  bf16* __restrict__ qb,
                                                  bf16* __restrict__ kb,
                                                  bf16* __restrict__ vb) {
    const int m0 = blockIdx.x * 128;
    const int n0 = blockIdx.y * 128;
    GEMM_MAINLOOP(A, Bt, m0, n0)
    const int col   = lane & 15;
    const int rbase = (lane >> 4) * 4;
    for (int nn = 0; nn < 4; ++nn) {
        int n = n0 + wc * 64 + nn * 16 + col;
        float bv = bias[n];
        int which = n >> 10;
        int c  = n & 1023;
        int h  = c >> 6;
        int dh = c & 63;
        bf16* dst = (which == 0) ? qb : ((which == 1) ? kb : vb);
        const float sc = (which == 0) ? CS_LOG2E : 1.0f;
        for (int mm = 0; mm < 4; ++mm) {
            for (int i = 0; i < 4; ++i) {
                int m = m0 + wr * 64 + mm * 16 + rbase + i;
                int b_ = m >> 11;
                int t  = m & 2047;
                dst[(((b_ * N_HEAD + h) * T_SEQ) + t) * HEAD_DIM + dh] =
                    f2b((acc[mm][nn][i] + bv) * sc);
            }
        }
    }
}

// ---------------- proj GEMM (64x128 tiles, R21 config) ----------------
__global__ __launch_bounds__(256) void k_gemm_proj(const bf16* __restrict__ A,
                                                   const bf16* __restrict__ Bt,
                                                   const float* __restrict__ bias,
                                                   float* __restrict__ out) {
    const int m0 = blockIdx.x * 64;
    const int n0 = blockIdx.y * 128;
    GEMM_MAINLOOP_64(A, Bt, m0, n0)
    const int col   = lane & 15;
    const int rbase = (lane >> 4) * 4;
    for (int nn = 0; nn < 4; ++nn) {
        int n = n0 + wc * 64 + nn * 16 + col;
        float bv = bias[n];
        for (int mm = 0; mm < 2; ++mm) {
            for (int i = 0; i < 4; ++i) {
                int m = m0 + wr * 32 + mm * 16 + rbase + i;
                out[(size_t)m * N_EMB + n] = acc[mm][nn][i] + bv;
            }
        }
    }
}

// =====================================================================
// flash attention helpers. Fixed-max softmax (Q pre-scaled, log2 units).
// R25 = R21 structure + ALL addresses hoisted out of the loop: the
// sched_barrier(0) in lds_fence blocks code motion, so any address math
// left inside recomputes every tile. Precomputed offsets live in
// registers; in-loop staging is base + t*stride + preoff.
// =====================================================================
__device__ __forceinline__ void pv_group(const float* p,
                                         const bf16x8 (&va)[2][2], f32x16 (&o)[2]) {
    u32x4 f0, f1;
    f0[0] = pkbf(p[0], p[1]);   f0[1] = pkbf(p[2], p[3]);
    f0[2] = pkbf(p[4], p[5]);   f0[3] = pkbf(p[6], p[7]);
    f1[0] = pkbf(p[8], p[9]);   f1[1] = pkbf(p[10], p[11]);
    f1[2] = pkbf(p[12], p[13]); f1[3] = pkbf(p[14], p[15]);
    bf16x8 pb0 = __builtin_bit_cast(bf16x8, f0);
    bf16x8 pb1 = __builtin_bit_cast(bf16x8, f1);
    __builtin_amdgcn_s_setprio(1);
    #pragma unroll
    for (int dt = 0; dt < 2; ++dt) {
        o[dt] = __builtin_amdgcn_mfma_f32_32x32x16_bf16(va[dt][0], pb0, o[dt], 0, 0, 0);
        o[dt] = __builtin_amdgcn_mfma_f32_32x32x16_bf16(va[dt][1], pb1, o[dt], 0, 0, 0);
    }
    __builtin_amdgcn_s_setprio(0);
}

__device__ __forceinline__ f32x16 qkt_tile(const bf16x8 (&kf)[4], const bf16x8 (&qf)[4]) {
    f32x16 st;
    #pragma unroll
    for (int r = 0; r < 16; ++r) st[r] = 0.f;
    __builtin_amdgcn_s_setprio(1);
    #pragma unroll
    for (int f = 0; f < 4; ++f)
        st = __builtin_amdgcn_mfma_f32_32x32x16_bf16(kf[f], qf[f], st, 0, 0, 0);
    __builtin_amdgcn_s_setprio(0);
    return st;
}

__device__ __forceinline__ void softmax_pv(f32x16 st, const bf16x8 (&va)[2][2],
                                           int qr, int hi, bool diag,
                                           float& l_r, f32x16 (&o)[2]) {
    if (diag) {
        const int kp4 = 4 * hi;
        #pragma unroll
        for (int r = 0; r < 16; ++r) {
            const int kpos = (r & 3) + 8 * (r >> 2) + kp4;
            if (kpos > qr) st[r] = -3.0e38f;
        }
    }
    float p[16];
    #pragma unroll
    for (int r = 0; r < 16; ++r) p[r] = exp2f(st[r]);   // masked -3e38 underflows to 0
    float s = 0.f;
    #pragma unroll
    for (int r = 0; r < 8; ++r) s += p[r] + p[r + 8];
    l_r += s;
    pv_group(p, va, o);
}

// =====================================================================
// flash attention: block = (bh, qblk), 4 waves, 4-way split-K. Each wave
// has a PRIVATE 8KB LDS slice, self-synced (no barriers in the loop).
// Staging of tile t+1 overlaps compute of t. All per-lane addresses
// precomputed before the loop. 32KB LDS. 2048 blocks, heavy-first,
// XCD-pinned bh. Combine: bf16 slabs + f32 l in own slice.
// =====================================================================
__global__ __launch_bounds__(256) void k_attn(const bf16* __restrict__ qb,
                                              const bf16* __restrict__ kb,
                                              const bf16* __restrict__ vtb,
                                              bf16* __restrict__ yb) {
    const int lane = threadIdx.x & 63;
    const int wv   = threadIdx.x >> 6;   // 0..3
    const int bh   = blockIdx.x;         // 0..31  (XCD = bh % 8)
    const int qblk = 63 - blockIdx.y;    // heavy-first
    const int q0   = qblk * 32;
    const int b    = bh >> 4;
    const int h    = bh & 15;

    const char* Qg = (const char*)(qb  + (size_t)bh * T_SEQ * HEAD_DIM);
    const char* Kg = (const char*)(kb  + (size_t)bh * T_SEQ * HEAD_DIM);
    const char* Vg = (const char*)(vtb + (size_t)bh * HEAD_DIM * T_SEQ);

    const int qr = lane & 31;
    const int hi = lane >> 5;

    __shared__ __align__(16) char sbuf[4][8192];   // per-wave private slice; 32KB
    char* Ks = sbuf[wv];
    char* Vs = sbuf[wv] + 4096;

    // ---- precompute ALL loop-invariant per-lane addresses (held in regs;
    //      the in-loop sched_barrier cannot force recomputation) ----
    // staging: K granule rr -> global off (fb^swz), LDS dest Ks+rr*1024
    int kg_off[4], vg_off[4];
    lptr_t kl_dst[4], vl_dst[4];
    #pragma unroll
    for (int rr = 0; rr < 4; ++rr) {
        const int fb = rr * 1024 + lane * 16;
        kg_off[rr] = fb ^ (((fb >> 7) & 7) << 4);                      // (row&7)<<4
        const int d = fb >> 6;
        vg_off[rr] = d * (T_SEQ * 2) + ((fb & 63) ^ ((d & 3) << 4));   // d*4096/2B rows
        kl_dst[rr] = (lptr_t)(void*)(Ks + rr * 1024);
        vl_dst[rr] = (lptr_t)(void*)(Vs + rr * 1024);
    }
    // fragment ds_read addresses (loop-invariant)
    const bf16x8* kf_src[4];
    const bf16x8* va_src[2][2];
    {
        const int swzk = (qr & 7) << 4;
        #pragma unroll
        for (int f = 0; f < 4; ++f)
            kf_src[f] = reinterpret_cast<const bf16x8*>(
                Ks + ((qr * 128 + f * 32 + hi * 16) ^ swzk));
        #pragma unroll
        for (int dt = 0; dt < 2; ++dt)
            #pragma unroll
            for (int ks = 0; ks < 2; ++ks) {
                const int d = dt * 32 + qr;
                va_src[dt][ks] = reinterpret_cast<const bf16x8*>(
                    Vs + ((d * 64 + ks * 32 + hi * 16) ^ ((d & 3) << 4)));
            }
    }

    // ---- Q fragments: stage via own slice (coalesced), then read ----
    #pragma unroll
    for (int rr = 0; rr < 4; ++rr)
        __builtin_amdgcn_global_load_lds(
            (gptr_t)(const void*)(Qg + (size_t)q0 * 128 + kg_off[rr]),
            kl_dst[rr], 16, 0, 0);
    asm volatile("s_waitcnt vmcnt(0)" ::: "memory");
    bf16x8 qf[4];
    #pragma unroll
    for (int f = 0; f < 4; ++f) qf[f] = *kf_src[f];
    lds_fence();   // RACE FIX (R17): qf reads drained before K staging overwrites

    f32x16 o[2];
    #pragma unroll
    for (int r = 0; r < 16; ++r) { o[0][r] = 0.f; o[1][r] = 0.f; }
    float l_r = 0.f;

    // 4-way split-K: wave wv owns a contiguous chunk; last chunk has diag.
    const int n    = qblk + 1;
    const int base = n >> 2;
    const int rem  = n & 3;
    const int lo   = wv * base + (wv < rem ? wv : rem);
    const int cnt  = base + (wv < rem ? 1 : 0);
    const int end  = lo + cnt;

    if (cnt > 0) {
        const char* Kc = Kg + (size_t)lo * 4096;   // 32 rows x 128B per tile
        const char* Vc = Vg + (size_t)lo * 64;     // 32 t-cols x 2B per tile
        #pragma unroll
        for (int rr = 0; rr < 4; ++rr)
            __builtin_amdgcn_global_load_lds((gptr_t)(const void*)(Kc + kg_off[rr]),
                                             kl_dst[rr], 16, 0, 0);
        #pragma unroll
        for (int rr = 0; rr < 4; ++rr)
            __builtin_amdgcn_global_load_lds((gptr_t)(const void*)(Vc + vg_off[rr]),
                                             vl_dst[rr], 16, 0, 0);
        for (int t = lo; t < end; ++t) {
            asm volatile("s_waitcnt vmcnt(0)" ::: "memory");   // tile t resident
            bf16x8 kf[4], va[2][2];
            #pragma unroll
            for (int f = 0; f < 4; ++f) kf[f] = *kf_src[f];
            f32x16 st = qkt_tile(kf, qf);      // waits kf only; overlaps va reads
            #pragma unroll
            for (int dt = 0; dt < 2; ++dt)
                #pragma unroll
                for (int ks = 0; ks < 2; ++ks) va[dt][ks] = *va_src[dt][ks];
            lds_fence();                       // all ds_reads drained
            if (t + 1 < end) {                 // stage t+1 under softmax+PV of t
                const char* Kn = Kc + 4096;
                const char* Vn = Vc + 64;
                #pragma unroll
                for (int rr = 0; rr < 4; ++rr)
                    __builtin_amdgcn_global_load_lds(
                        (gptr_t)(const void*)(Kn + kg_off[rr]), kl_dst[rr], 16, 0, 0);
                #pragma unroll
                for (int rr = 0; rr < 4; ++rr)
                    __builtin_amdgcn_global_load_lds(
                        (gptr_t)(const void*)(Vn + vg_off[rr]), vl_dst[rr], 16, 0, 0);
                Kc = Kn; Vc = Vn;
            }
            softmax_pv(st, va, qr, hi, t == qblk, l_r, o);
        }
    }

    // ---- combine across 4 waves via own slice: bf16 o slab + f32 l ----
    if (wv > 0) {
        bf16* so = (bf16*)sbuf[wv];
        #pragma unroll
        for (int i = 0; i < 16; ++i) {
            so[i * 64 + lane]        = f2b(o[0][i]);
            so[(16 + i) * 64 + lane] = f2b(o[1][i]);
        }
        *reinterpret_cast<float*>(sbuf[wv] + 4096 + lane * 4) = l_r;
    }
    __syncthreads();
    if (wv > 0) return;
    #pragma unroll
    for (int s = 1; s < 4; ++s) {
        const bf16* so = (const bf16*)sbuf[s];
        l_r += *reinterpret_cast<const float*>(sbuf[s] + 4096 + lane * 4);
        #pragma unroll
        for (int i = 0; i < 16; ++i) {
            o[0][i] += (float)so[i * 64 + lane];
            o[1][i] += (float)so[(16 + i) * 64 + lane];
        }
    }
    l_r = xhalf_sum(l_r);

    // ---- epilogue: O^T[d][q] / l -> y[b][t][h*64+d] ----
    const float inv = 1.f / fmaxf(l_r, 1e-30f);
    const int tq = q0 + qr;
    bf16* yrow = yb + ((size_t)(b * T_SEQ + tq)) * N_EMB + h * HEAD_DIM;
    #pragma unroll
    for (int dt = 0; dt < 2; ++dt) {
        #pragma unroll
        for (int rr = 0; rr < 4; ++rr) {
            const int d0 = dt * 32 + 8 * rr + 4 * hi;
            ushort4 u;
            u.x = f2bu(o[dt][4 * rr + 0] * inv);
            u.y = f2bu(o[dt][4 * rr + 1] * inv);
            u.z = f2bu(o[dt][4 * rr + 2] * inv);
            u.w = f2bu(o[dt][4 * rr + 3] * inv);
            *reinterpret_cast<ushort4*>(yrow + d0) = u;
        }
    }
}

extern "C" void kernel_launch(void* const* d_in, const int* in_sizes, int n_in,
                              void* d_out, int out_size, void* d_ws, size_t ws_size,
                              hipStream_t stream) {
    const float* x      = (const float*)d_in[0];
    const float* W_attn = (const float*)d_in[1];
    const float* b_attn = (const float*)d_in[2];
    const float* W_proj = (const float*)d_in[3];
    const float* b_proj = (const float*)d_in[4];
    float* out = (float*)d_out;

    const size_t sz_x   = (size_t)M_TOT * N_EMB;
    const size_t sz_wat = (size_t)N_QKV * N_EMB;
    const size_t sz_wpt = (size_t)N_EMB * N_EMB;
    const size_t sz_hd  = (size_t)BATCH * N_HEAD * T_SEQ * HEAD_DIM;
    const size_t need = (sz_x + sz_wat + sz_wpt + 3 * sz_hd + sz_x) * sizeof(bf16);
    if (ws_size < need) return;

    bf16* xb  = (bf16*)d_ws;       // dead after QKV GEMM -> reused for V^T
    bf16* wat = xb + sz_x;
    bf16* wpt = wat + sz_wat;
    bf16* qb  = wpt + sz_wpt;
    bf16* kbf = qb + sz_hd;
    bf16* vbf = kbf + sz_hd;
    bf16* yb  = vbf + sz_hd;
    bf16* vtb = xb;                // V^T [B,H,64,T] (k-permuted)

    k_prep<<<dim3(8192), 256, 0, stream>>>(x, W_attn, W_proj, xb, wat, wpt);
    k_gemm_qkv<<<dim3(M_TOT / 128, N_QKV / 128), 256, 0, stream>>>(xb, wat, b_attn, qb, kbf, vbf);
    k_vtrans<<<dim3(T_SEQ / 64, BATCH * N_HEAD), 256, 0, stream>>>(vbf, vtb);
    k_attn<<<dim3(BATCH * N_HEAD, 64), 256, 0, stream>>>(qb, kbf, vtb, yb);
    k_gemm_proj<<<dim3(M_TOT / 64, N_EMB / 128), 256, 0, stream>>>(yb, wpt, b_proj, out);
}